// Round 8
// baseline (352.496 us; speedup 1.0000x reference)
//
#include <hip/hip_runtime.h>
#include <hip/hip_cooperative_groups.h>
#include <math.h>

namespace cg = cooperative_groups;

// Problem constants
#define HN 8
#define DK 64
#define LQ 4096
#define LKV 1024
#define DMODEL 512
#define BATCH 2
#define NBLK 256   // 1 block/CU -> co-residency guaranteed for cooperative launch

typedef unsigned short u16;
typedef unsigned int u32;
typedef __attribute__((ext_vector_type(8))) __bf16 bf16x8;
typedef __attribute__((ext_vector_type(4))) float f32x4;
typedef __attribute__((ext_vector_type(8))) u16 u16x8;

// fp32 -> bf16 round-to-nearest-even (finite inputs only)
__device__ __forceinline__ u16 f2bf(float f) {
    u32 u = __float_as_uint(f);
    u = u + 0x7fffu + ((u >> 16) & 1u);
    return (u16)(u >> 16);
}
__device__ __forceinline__ float bf2f(u16 u) {
    return __uint_as_float(((u32)u) << 16);
}

// async 16B global -> LDS (wave-uniform LDS base; HW writes base + lane*16)
__device__ __forceinline__ void gl_lds16(const u16* g, u16* l) {
    __builtin_amdgcn_global_load_lds((const __attribute__((address_space(1))) u32*)g,
                                     (__attribute__((address_space(3))) u32*)l, 16, 0, 0);
}

struct GemmSm { u16 As[128 * 32]; u16 Bs[128 * 32]; };     // 16 KB
struct AttnSm { float Ks[80][68]; float Vs[80][68]; };     // 43.5 KB
union MegaSm { GemmSm g; AttnSm a; float tbuf[32][33]; };

// ---------------------------------------------------------------------------
// R3-proven bf16 MFMA GEMM tile (128x128, BK=32, 4 waves 2x2, 4x4 MFMA/wave).
// ---------------------------------------------------------------------------
template <bool BF16OUT>
__device__ __forceinline__ void gemm_tile(const u16* A, const u16* Bt, void* Cp,
                                          int bx, int by, GemmSm& sg) {
    const int tid = threadIdx.x;
    const int lane = tid & 63;
    const int wave = tid >> 6;
    const int wm = (wave >> 1) * 64;
    const int wn = (wave & 1) * 64;
    const int quad = lane >> 4;
    const int l16 = lane & 15;
    const size_t m0 = (size_t)by * 128;
    const size_t n0 = (size_t)bx * 128;

    f32x4 acc[4][4] = {};

    for (int k0 = 0; k0 < 512; k0 += 32) {
#pragma unroll
        for (int i = 0; i < 2; ++i) {
            const int id = i * 256 + tid;
            const int r = id >> 2;
            const int cs = id & 3;
            const int c = cs ^ ((r >> 1) & 3);
            gl_lds16(&A[(m0 + r) * 512 + k0 + c * 8], &sg.As[(size_t)(i * 256 + wave * 64) * 8]);
            gl_lds16(&Bt[(n0 + r) * 512 + k0 + c * 8], &sg.Bs[(size_t)(i * 256 + wave * 64) * 8]);
        }
        __syncthreads();

        bf16x8 af[4], bfr[4];
#pragma unroll
        for (int i = 0; i < 4; ++i) {
            const int ra = wm + i * 16 + l16;
            const int ca = quad ^ ((ra >> 1) & 3);
            af[i] = *(const bf16x8*)&sg.As[ra * 32 + ca * 8];
            const int rb = wn + i * 16 + l16;
            const int cb = quad ^ ((rb >> 1) & 3);
            bfr[i] = *(const bf16x8*)&sg.Bs[rb * 32 + cb * 8];
        }
#pragma unroll
        for (int i = 0; i < 4; ++i)
#pragma unroll
            for (int j = 0; j < 4; ++j)
                acc[i][j] = __builtin_amdgcn_mfma_f32_16x16x32_bf16(af[i], bfr[j], acc[i][j], 0, 0, 0);
        __syncthreads();
    }

#pragma unroll
    for (int i = 0; i < 4; ++i) {
#pragma unroll
        for (int j = 0; j < 4; ++j) {
            const size_t row = m0 + wm + i * 16 + quad * 4;
            const size_t col = n0 + wn + j * 16 + l16;
#pragma unroll
            for (int t = 0; t < 4; ++t) {
                if (BF16OUT)
                    ((u16*)Cp)[(row + t) * 512 + col] = f2bf(acc[i][j][t]);
                else
                    ((float*)Cp)[(row + t) * 512 + col] = acc[i][j][t];
            }
        }
    }
}

// ---------------------------------------------------------------------------
// Attention tile: 256 queries, 80-row K/V window in LDS, fp32 compute.
// For query c: fd = floor((63-c)/4); KV col(r) = r - fd, valid iff r >= fd.
// ---------------------------------------------------------------------------
__device__ __forceinline__ void attn_tile(const u16* Q, const u16* K, const u16* V,
                                          u16* ctx, int cblk, int h, int b, AttnSm& sa) {
    const int tid = threadIdx.x;
    const int c0 = cblk * 256;
    const int fd_c0 = (63 - c0) >> 2;
    const int win_lo = (fd_c0 < 0) ? -fd_c0 : 0;

    for (int i = tid; i < 80 * 8; i += 256) {
        int row = i >> 3;
        int d8 = i & 7;
        int col = win_lo + row;
        if (col < LKV) {
            size_t base = ((size_t)(b * LKV + col)) * DMODEL + h * DK + d8 * 8;
            u16x8 k8 = *(const u16x8*)&K[base];
            u16x8 v8 = *(const u16x8*)&V[base];
            *(float4*)&sa.Ks[row][d8 * 8]     = make_float4(bf2f(k8[0]), bf2f(k8[1]), bf2f(k8[2]), bf2f(k8[3]));
            *(float4*)&sa.Ks[row][d8 * 8 + 4] = make_float4(bf2f(k8[4]), bf2f(k8[5]), bf2f(k8[6]), bf2f(k8[7]));
            *(float4*)&sa.Vs[row][d8 * 8]     = make_float4(bf2f(v8[0]), bf2f(v8[1]), bf2f(v8[2]), bf2f(v8[3]));
            *(float4*)&sa.Vs[row][d8 * 8 + 4] = make_float4(bf2f(v8[4]), bf2f(v8[5]), bf2f(v8[6]), bf2f(v8[7]));
        }
    }
    __syncthreads();

    const int c = c0 + tid;
    const int fd = (63 - c) >> 2;

    float4 qv[16];
    const u16* qp = &Q[((size_t)(b * LQ + c)) * DMODEL + h * DK];
#pragma unroll
    for (int i = 0; i < 8; ++i) {
        u16x8 t8 = *(const u16x8*)&qp[i * 8];
        qv[i * 2]     = make_float4(bf2f(t8[0]), bf2f(t8[1]), bf2f(t8[2]), bf2f(t8[3]));
        qv[i * 2 + 1] = make_float4(bf2f(t8[4]), bf2f(t8[5]), bf2f(t8[6]), bf2f(t8[7]));
    }

    float sc[16];
    float mx = -3.0e38f;
#pragma unroll
    for (int r = 0; r < 16; ++r) {
        int col = r - fd;
        if (col < 0) col = 0;
        const float4* kr = (const float4*)&sa.Ks[col - win_lo][0];
        float s = 0.f;
#pragma unroll
        for (int i = 0; i < 16; ++i) {
            float4 kv = kr[i];
            s += qv[i].x * kv.x + qv[i].y * kv.y + qv[i].z * kv.z + qv[i].w * kv.w;
        }
        s *= 0.125f;
        sc[r] = (r >= fd) ? s : -1.0e30f;
        mx = fmaxf(mx, sc[r]);
    }

    float sum = 0.f;
#pragma unroll
    for (int r = 0; r < 16; ++r) {
        sc[r] = __expf(sc[r] - mx);
        sum += sc[r];
    }
    const float inv = 1.0f / sum;

    float4 acc4[16];
#pragma unroll
    for (int i = 0; i < 16; ++i) acc4[i] = make_float4(0.f, 0.f, 0.f, 0.f);
#pragma unroll
    for (int r = 0; r < 16; ++r) {
        const float w = sc[r] * inv;
        int col = r - fd;
        if (col < 0) col = 0;
        const float4* vr = (const float4*)&sa.Vs[col - win_lo][0];
#pragma unroll
        for (int i = 0; i < 16; ++i) {
            float4 vv = vr[i];
            acc4[i].x = fmaf(w, vv.x, acc4[i].x);
            acc4[i].y = fmaf(w, vv.y, acc4[i].y);
            acc4[i].z = fmaf(w, vv.z, acc4[i].z);
            acc4[i].w = fmaf(w, vv.w, acc4[i].w);
        }
    }

    u16* cp = &ctx[((size_t)(b * LQ + c)) * DMODEL + h * DK];
#pragma unroll
    for (int i = 0; i < 8; ++i) {
        u16x8 o;
        o[0] = f2bf(acc4[i * 2].x);     o[1] = f2bf(acc4[i * 2].y);
        o[2] = f2bf(acc4[i * 2].z);     o[3] = f2bf(acc4[i * 2].w);
        o[4] = f2bf(acc4[i * 2 + 1].x); o[5] = f2bf(acc4[i * 2 + 1].y);
        o[6] = f2bf(acc4[i * 2 + 1].z); o[7] = f2bf(acc4[i * 2 + 1].w);
        *(u16x8*)&cp[i * 8] = o;
    }
}

// ---------------------------------------------------------------------------
// Prep job (shared by mega and fallback): cvt q/k/v (jobs 0..3071) or
// weight transpose (jobs 3072..4095).
// ---------------------------------------------------------------------------
__device__ __forceinline__ void prep_job(int job, int tid,
                                         const float* q, const float* k, const float* v,
                                         const float* Wq, const float* Wk,
                                         const float* Wv, const float* Wout,
                                         u16* qb, u16* kb, u16* vb,
                                         u16* wqt, u16* wkt, u16* wvt, u16* wot,
                                         float (*tbuf)[33]) {
    if (job < 3072) {
        const float* in;
        u16* outp;
        int i;
        if (job < 2048)      { in = q; outp = qb; i = job * 256 + tid; }
        else if (job < 2560) { in = k; outp = kb; i = (job - 2048) * 256 + tid; }
        else                 { in = v; outp = vb; i = (job - 2560) * 256 + tid; }
        const float4 a = ((const float4*)in)[i * 2];
        const float4 b4 = ((const float4*)in)[i * 2 + 1];
        u16x8 r;
        r[0] = f2bf(a.x);  r[1] = f2bf(a.y);  r[2] = f2bf(a.z);  r[3] = f2bf(a.w);
        r[4] = f2bf(b4.x); r[5] = f2bf(b4.y); r[6] = f2bf(b4.z); r[7] = f2bf(b4.w);
        *(u16x8*)&outp[(size_t)i * 8] = r;
    } else {
        const int wb = job - 3072;
        const int z = wb >> 8;
        const int t = wb & 255;
        const float* W = (z == 0) ? Wq : (z == 1) ? Wk : (z == 2) ? Wv : Wout;
        u16* O = (z == 0) ? wqt : (z == 1) ? wkt : (z == 2) ? wvt : wot;
        const int tx = tid & 31;
        const int ty = tid >> 5;
        const int x = (t & 15) * 32 + tx;
        const int y0 = (t >> 4) * 32;
        __syncthreads();
#pragma unroll
        for (int i = ty; i < 32; i += 8) tbuf[i][tx] = W[(size_t)(y0 + i) * 512 + x];
        __syncthreads();
#pragma unroll
        for (int i = ty; i < 32; i += 8)
            O[(size_t)((t & 15) * 32 + i) * 512 + y0 + tx] = f2bf(tbuf[tx][i]);
    }
}

// ---------------------------------------------------------------------------
// Cooperative mega-kernel: prep -> proj -> attn -> out-proj, job-looped so any
// grid size works; NBLK=256 guarantees co-residency (1 block/CU).
// ---------------------------------------------------------------------------
__global__ __launch_bounds__(256) void mega(const float* q, const float* k, const float* v,
                                            const float* Wq, const float* Wk,
                                            const float* Wv, const float* Wout,
                                            u16* qb, u16* kb, u16* vb,
                                            u16* wqt, u16* wkt, u16* wvt, u16* wot,
                                            u16* Qb, u16* Kb, u16* Vb, u16* cb,
                                            float* out) {
    cg::grid_group grid = cg::this_grid();
    __shared__ MegaSm sm;
    const int bid = blockIdx.x;
    const int tid = threadIdx.x;
    const int nb = gridDim.x;

    // Phase 0: prep, 4096 jobs
    for (int job = bid; job < 4096; job += nb)
        prep_job(job, tid, q, k, v, Wq, Wk, Wv, Wout, qb, kb, vb, wqt, wkt, wvt, wot, sm.tbuf);
    __threadfence();
    grid.sync();

    // Phase 1: Q/K/V projections, 384 jobs
    for (int job = bid; job < 384; job += nb) {
        if (job < 256)
            gemm_tile<true>(qb, wqt, Qb, job & 3, job >> 2, sm.g);
        else if (job < 320)
            gemm_tile<true>(kb, wkt, Kb, (job - 256) & 3, (job - 256) >> 2, sm.g);
        else
            gemm_tile<true>(vb, wvt, Vb, (job - 320) & 3, (job - 320) >> 2, sm.g);
        __syncthreads();
    }
    __threadfence();
    grid.sync();

    // Phase 2: attention, 256 jobs
    for (int job = bid; job < 256; job += nb) {
        attn_tile(Qb, Kb, Vb, cb, job & 15, (job >> 4) & 7, job >> 7, sm.a);
        __syncthreads();
    }
    __threadfence();
    grid.sync();

    // Phase 3: output projection, 256 jobs
    for (int job = bid; job < 256; job += nb) {
        gemm_tile<false>(cb, wot, out, job & 3, job >> 2, sm.g);
        __syncthreads();
    }
}

// ---------------------------------------------------------------------------
// Fallback kernels (R3-proven 4-launch path), sharing the device functions.
// ---------------------------------------------------------------------------
__global__ __launch_bounds__(256) void prep_k(const float* q, const float* k, const float* v,
                                              const float* Wq, const float* Wk,
                                              const float* Wv, const float* Wout,
                                              u16* qb, u16* kb, u16* vb,
                                              u16* wqt, u16* wkt, u16* wvt, u16* wot) {
    __shared__ float tbuf[32][33];
    prep_job(blockIdx.x, threadIdx.x, q, k, v, Wq, Wk, Wv, Wout,
             qb, kb, vb, wqt, wkt, wvt, wot, tbuf);
}

__global__ __launch_bounds__(256) void proj_k(const u16* qb, const u16* kb, const u16* vb,
                                              const u16* wqt, const u16* wkt, const u16* wvt,
                                              u16* Qb, u16* Kb, u16* Vb) {
    __shared__ GemmSm sg;
    const int idx = blockIdx.x;
    if (idx < 256)
        gemm_tile<true>(qb, wqt, Qb, idx & 3, idx >> 2, sg);
    else if (idx < 320)
        gemm_tile<true>(kb, wkt, Kb, (idx - 256) & 3, (idx - 256) >> 2, sg);
    else
        gemm_tile<true>(vb, wvt, Vb, (idx - 320) & 3, (idx - 320) >> 2, sg);
}

__global__ __launch_bounds__(256) void attn_k(const u16* Q, const u16* K, const u16* V,
                                              u16* ctx) {
    __shared__ AttnSm sa;
    attn_tile(Q, K, V, ctx, blockIdx.x, blockIdx.y, blockIdx.z, sa);
}

__global__ __launch_bounds__(256) void out_k(const u16* A, const u16* Bt, float* C) {
    __shared__ GemmSm sg;
    gemm_tile<false>(A, Bt, C, blockIdx.x & 3, blockIdx.x >> 2, sg);
}

// ---------------------------------------------------------------------------
extern "C" void kernel_launch(void* const* d_in, const int* in_sizes, int n_in,
                              void* d_out, int out_size, void* d_ws, size_t ws_size,
                              hipStream_t stream) {
    const float* q    = (const float*)d_in[0];
    const float* k    = (const float*)d_in[1];
    const float* v    = (const float*)d_in[2];
    const float* Wq   = (const float*)d_in[3];
    const float* Wk   = (const float*)d_in[4];
    const float* Wv   = (const float*)d_in[5];
    const float* Wout = (const float*)d_in[6];
    float* out = (float*)d_out;

    const size_t NQ = (size_t)BATCH * LQ * DMODEL;   // 4,194,304
    const size_t NK = (size_t)BATCH * LKV * DMODEL;  // 1,048,576
    const size_t NW = (size_t)DMODEL * DMODEL;       //   262,144

    u16* qb  = (u16*)d_ws;
    u16* kb  = qb + NQ;
    u16* vb  = kb + NK;
    u16* Qb  = vb + NK;
    u16* Kb  = Qb + NQ;
    u16* Vb  = Kb + NK;
    u16* cb  = Vb + NK;
    u16* wqt = cb + NQ;
    u16* wkt = wqt + NW;
    u16* wvt = wkt + NW;
    u16* wot = wvt + NW;

    void* args[] = {&q, &k, &v, &Wq, &Wk, &Wv, &Wout,
                    &qb, &kb, &vb, &wqt, &wkt, &wvt, &wot,
                    &Qb, &Kb, &Vb, &cb, &out};
    hipError_t err = hipLaunchCooperativeKernel((const void*)mega, dim3(NBLK), dim3(256),
                                                args, 0, stream);
    if (err != hipSuccess) {
        // Fallback: proven 4-kernel sequence (R3 structure)
        prep_k<<<dim3(4096), dim3(256), 0, stream>>>(q, k, v, Wq, Wk, Wv, Wout,
                                                     qb, kb, vb, wqt, wkt, wvt, wot);
        proj_k<<<dim3(384), dim3(256), 0, stream>>>(qb, kb, vb, wqt, wkt, wvt, Qb, Kb, Vb);
        attn_k<<<dim3(16, HN, BATCH), dim3(256), 0, stream>>>(Qb, Kb, Vb, cb);
        out_k<<<dim3(256), dim3(256), 0, stream>>>(cb, wot, out);
    }
}